// Round 1
// baseline (155.793 us; speedup 1.0000x reference)
//
#include <hip/hip_runtime.h>

// FFTPermuter: out_chunk[c][col] = x[8*col + ms[c]], ms = {0,4,2,6,1,5,3,7}
// (bit-reversal on the low 3 bits of the float index; ms is an involution).
//
// R6: invert the permutation onto the STORE side, where it is cheap.
// For global float index I: chunk = bitrev3(I & 7), col = I >> 3.
// A thread loading one coalesced float4 (I = 4f..4f+3) writes its 4
// components to 4 different chunks at the SAME col = f>>1:
//     chunk(e) = {0,4,2,6}[e] + (f & 1)
// Per store instruction the wave's 64 lanes cover exactly TWO complete
// 128B-aligned lines (even-f lanes -> chunk base+0, odd-f -> base+1).
// => loads perfectly coalesced (8 fully-used lines/instr), stores
// line-coalesced dword scatter, no LDS, no shuffles, no transpose.
// R0-R5 all paid for the transpose somewhere (64-line strided loads here,
// LDS/barriers there) and pinned at 2.4-2.6 TB/s; this removes it entirely.

typedef float v4f __attribute__((ext_vector_type(4)));

#define BLOCK     256
#define GRID      2048
#define NTHREADS  (GRID * BLOCK)         // 524288 threads
#define KPT       8                      // float4s per thread; 2^22 total

__global__ __launch_bounds__(BLOCK) void
FFTPermuter_2748779070248_kernel(const v4f* __restrict__ x4,
                                 float* __restrict__ out) {
    const unsigned t = blockIdx.x * BLOCK + threadIdx.x;

    // All loads first: 8 outstanding, fully coalesced (lane-consecutive).
    v4f v[KPT];
#pragma unroll
    for (int n = 0; n < KPT; ++n)
        v[n] = x4[(size_t)t + (size_t)n * NTHREADS];

#pragma unroll
    for (int n = 0; n < KPT; ++n) {
        const unsigned f   = t + (unsigned)n * NTHREADS;  // global float4 idx
        const unsigned col = f >> 1;                      // same for all 4 comps
        const size_t   lo  = f & 1;                       // chunk low bit
        // chunk = {0,4,2,6}[e] + lo ; each chunk is 2^21 floats (8 MiB)
        __builtin_nontemporal_store(v[n].x, &out[((0 + lo) << 21) + col]);
        __builtin_nontemporal_store(v[n].y, &out[((4 + lo) << 21) + col]);
        __builtin_nontemporal_store(v[n].z, &out[((2 + lo) << 21) + col]);
        __builtin_nontemporal_store(v[n].w, &out[((6 + lo) << 21) + col]);
    }
}

extern "C" void kernel_launch(void* const* d_in, const int* in_sizes, int n_in,
                              void* d_out, int out_size, void* d_ws, size_t ws_size,
                              hipStream_t stream) {
    const v4f* x4  = (const v4f*)d_in[0];  // x: [8,512,4096] fp32, 2^22 float4s
    float*     out = (float*)d_out;        // 8 chunks of [8,512,512] fp32

    FFTPermuter_2748779070248_kernel<<<GRID, BLOCK, 0, stream>>>(x4, out);
}

// Round 2
// 149.700 us; speedup vs baseline: 1.0407x; 1.0407x over previous
//
#include <hip/hip_runtime.h>

// FFTPermuter: out_chunk[c][col] = x[8*col + ms[c]], ms = {0,4,2,6,1,5,3,7}
// (bit-reversal on the low 3 bits of the float index).
//
// R7: R6 structure verbatim (coalesced float4 loads, store-side permutation
// with 2-line dword stores, NT stores) with ONE change: NON-TEMPORAL LOADS.
// Evidence: R0-R6 swept access pattern (load-strided / LDS / store-scatter /
// both-sides-coalesced), occupancy (14-53%), and store policy (cached/NT) —
// ALL pin at 42-43 us, 2.35-2.6 TB/s counted, with zero overfetch
// (FETCH 33MB + WRITE 65.5MB exact). Write-only fill hits 6.6 TB/s in the
// same poisoned-cache harness => the read path is the differentiator.
// At ~900cy miss latency, 43 us implies only ~36 outstanding line-fills/CU
// (need ~72 for 6.3 TB/s) — consistent with an L1 fill-slot cap, which is
// pattern-INDEPENDENT, matching six identical-time structures. NT loads
// skip L1/L2 allocation (nothing is ever re-read; 16 waves x 1KB/instr
// thrash the 32KiB L1 8x over anyway) and ride the deeper fabric queues.

typedef float v4f __attribute__((ext_vector_type(4)));

#define BLOCK     256
#define GRID      2048
#define NTHREADS  (GRID * BLOCK)         // 524288 threads
#define KPT       8                      // float4s per thread; 2^22 total

__global__ __launch_bounds__(BLOCK) void
FFTPermuter_2748779070248_kernel(const v4f* __restrict__ x4,
                                 float* __restrict__ out) {
    const unsigned t = blockIdx.x * BLOCK + threadIdx.x;

    // All loads first: 8 outstanding per wave, fully lane-coalesced,
    // NON-TEMPORAL (no L1/L2 allocate, deeper outstanding capacity).
    v4f v[KPT];
#pragma unroll
    for (int n = 0; n < KPT; ++n)
        v[n] = __builtin_nontemporal_load(&x4[(size_t)t + (size_t)n * NTHREADS]);

#pragma unroll
    for (int n = 0; n < KPT; ++n) {
        const unsigned f   = t + (unsigned)n * NTHREADS;  // global float4 idx
        const unsigned col = f >> 1;                      // same for all 4 comps
        const size_t   lo  = f & 1;                       // chunk low bit
        // chunk = {0,4,2,6}[e] + lo ; each chunk is 2^21 floats (8 MiB)
        __builtin_nontemporal_store(v[n].x, &out[((0 + lo) << 21) + col]);
        __builtin_nontemporal_store(v[n].y, &out[((4 + lo) << 21) + col]);
        __builtin_nontemporal_store(v[n].z, &out[((2 + lo) << 21) + col]);
        __builtin_nontemporal_store(v[n].w, &out[((6 + lo) << 21) + col]);
    }
}

extern "C" void kernel_launch(void* const* d_in, const int* in_sizes, int n_in,
                              void* d_out, int out_size, void* d_ws, size_t ws_size,
                              hipStream_t stream) {
    const v4f* x4  = (const v4f*)d_in[0];  // x: [8,512,4096] fp32, 2^22 float4s
    float*     out = (float*)d_out;        // 8 chunks of [8,512,512] fp32

    FFTPermuter_2748779070248_kernel<<<GRID, BLOCK, 0, stream>>>(x4, out);
}

// Round 3
// 149.399 us; speedup vs baseline: 1.0428x; 1.0020x over previous
//
#include <hip/hip_runtime.h>

// FFTPermuter: out_chunk[c][col] = x[8*col + ms[c]], ms = {0,4,2,6,1,5,3,7}
// (bit-reversal on the low 3 bits of the float index).
//
// R8: R6/R7 indexing verbatim; cache policy escalated to FULL STREAMING
// (sc0 sc1 nt = system-scope non-temporal) on both loads and stores via
// inline asm. Theory: harness poison-fills leave L3 (256MB) dirty; every
// cached allocation we make evicts a dirty victim => hidden HBM writebacks
// (~64-128MB) that TCC counters never see. m13's clean-cache float4 copy
// does 6.29 TB/s mixed r+w, so the 64R+64W payload is worth ~20us; our pin
// at 38-43us is the eviction tax. nt-only (R7) weakened allocation and gave
// the first-ever gain (43 -> <40us); sc0+sc1+nt bypasses allocation at
// every level in both directions: zero poison evictions.
//
// Ordering discipline: all memory ops are volatile inline asm (loads ->
// s_waitcnt vmcnt(0) -> stores); volatile asm blocks are never reordered
// against each other, and the explicit vmcnt(0) covers the data hazard the
// compiler can't see through asm loads.

typedef float v4f __attribute__((ext_vector_type(4)));

#define BLOCK     256
#define GRID      2048
#define NTHREADS  (GRID * BLOCK)         // 524288 threads
#define KPT       8                      // float4s per thread; 2^22 total

__device__ __forceinline__ v4f load_stream(const v4f* p) {
    v4f r;
    asm volatile("global_load_dwordx4 %0, %1, off sc0 sc1 nt"
                 : "=v"(r) : "v"(p));
    return r;
}

__device__ __forceinline__ void store_stream(float* p, float v) {
    asm volatile("global_store_dword %0, %1, off sc0 sc1 nt"
                 :: "v"(p), "v"(v) : "memory");
}

__global__ __launch_bounds__(BLOCK) void
FFTPermuter_2748779070248_kernel(const v4f* __restrict__ x4,
                                 float* __restrict__ out) {
    const unsigned t = blockIdx.x * BLOCK + threadIdx.x;

    // Issue all 8 fully-coalesced streaming loads, then one full drain.
    v4f v[KPT];
#pragma unroll
    for (int n = 0; n < KPT; ++n)
        v[n] = load_stream(&x4[(size_t)t + (size_t)n * NTHREADS]);

    asm volatile("s_waitcnt vmcnt(0)" ::: "memory");

#pragma unroll
    for (int n = 0; n < KPT; ++n) {
        const unsigned f   = t + (unsigned)n * NTHREADS;  // global float4 idx
        const unsigned col = f >> 1;                      // same for all 4 comps
        const unsigned lo  = f & 1;                       // chunk low bit
        // chunk = {0,4,2,6}[e] + lo ; each chunk is 2^21 floats (8 MiB).
        // Per store instr the wave covers two complete 128B lines.
        store_stream(&out[(size_t)((0 + lo) << 21) + col], v[n].x);
        store_stream(&out[(size_t)((4 + lo) << 21) + col], v[n].y);
        store_stream(&out[(size_t)((2 + lo) << 21) + col], v[n].z);
        store_stream(&out[(size_t)((6 + lo) << 21) + col], v[n].w);
    }
}

extern "C" void kernel_launch(void* const* d_in, const int* in_sizes, int n_in,
                              void* d_out, int out_size, void* d_ws, size_t ws_size,
                              hipStream_t stream) {
    const v4f* x4  = (const v4f*)d_in[0];  // x: [8,512,4096] fp32, 2^22 float4s
    float*     out = (float*)d_out;        // 8 chunks of [8,512,512] fp32

    FFTPermuter_2748779070248_kernel<<<GRID, BLOCK, 0, stream>>>(x4, out);
}